// Round 1
// baseline (4376.493 us; speedup 1.0000x reference)
//
#include <hip/hip_runtime.h>
#include <cstddef>
#include <cstdint>

// Problem constants (fixed shapes from the reference)
constexpr int NN  = 100000;   // nodes
constexpr int EE  = 400000;   // edges
constexpr int SS  = 1024;     // supernodes
constexpr int EBB = 400000;   // bipartite edges
constexpr int ESS = 50000;    // superedges
constexpr int LF  = 128;      // feature dim
constexpr int HID = 256;      // hidden dim
// MLP: Linear(384,256) -> LN -> ReLU -> Linear(256,128) -> LN -> act, + residual

// ---------------------------------------------------------------------------
// Counting-sort infrastructure (index-only atomics; values summed atomic-free)
// ---------------------------------------------------------------------------
__global__ void k_hist(const int* __restrict__ idx, int n, int* __restrict__ hist) {
  for (int e = blockIdx.x * blockDim.x + threadIdx.x; e < n; e += gridDim.x * blockDim.x)
    atomicAdd(&hist[idx[e]], 1);
}

__global__ void k_scanA(const int* __restrict__ hist, int n,
                        int* __restrict__ off, int* __restrict__ csum) {
  __shared__ int sd[1024];
  const int t = threadIdx.x;
  const int i = blockIdx.x * 1024 + t;
  int v = (i < n) ? hist[i] : 0;
  sd[t] = v;
  __syncthreads();
  for (int d = 1; d < 1024; d <<= 1) {
    int addv = (t >= d) ? sd[t - d] : 0;
    __syncthreads();
    sd[t] += addv;
    __syncthreads();
  }
  if (i < n) off[i] = sd[t] - v;              // exclusive within chunk
  if (t == 1023) csum[blockIdx.x] = sd[t];    // chunk total
}

__global__ void k_scanB(int* __restrict__ csum, int nchunks) {
  if (threadIdx.x == 0 && blockIdx.x == 0) {
    int run = 0;
    for (int i = 0; i < nchunks; ++i) { int v = csum[i]; csum[i] = run; run += v; }
  }
}

__global__ void k_scanC(int* __restrict__ off, const int* __restrict__ hist,
                        const int* __restrict__ csum, int n, int* __restrict__ cur) {
  const int i = blockIdx.x * blockDim.x + threadIdx.x;
  if (i < n) {
    int o = off[i] + csum[i >> 10];
    off[i] = o;
    cur[i] = o;
    if (i == n - 1) off[n] = o + hist[i];
  }
}

__global__ void k_scatter(const int* __restrict__ idx, int n,
                          int* __restrict__ cur, int* __restrict__ order) {
  for (int e = blockIdx.x * blockDim.x + threadIdx.x; e < n; e += gridDim.x * blockDim.x) {
    int d = idx[e];
    int p = atomicAdd(&cur[d], 1);
    order[p] = e;
  }
}

// out[s][c] = sum_{e in seg(s)} w[e] * src[rowidx?rowidx[e]:e][c]
__global__ void k_gather(const int* __restrict__ off, const int* __restrict__ order,
                         const int* __restrict__ rowidx, const float* __restrict__ w,
                         const float* __restrict__ src, float* __restrict__ out) {
  const int s = blockIdx.x;
  const int c = threadIdx.x;
  const int p0 = off[s], p1 = off[s + 1];
  float acc = 0.f;
  #pragma unroll 4
  for (int p = p0; p < p1; ++p) {
    int e = order[p];
    int r = rowidx ? rowidx[e] : e;
    acc += w[e] * src[(size_t)r * LF + c];
  }
  out[(size_t)s * LF + c] = acc;
}

// ---------------------------------------------------------------------------
// Fused MLP: X(BMx384 gathered-concat) @ W1 -> +b1,LN,ReLU (in LDS)
//            -> @ W2 -> +b2,LN,act(+residual) -> out
// Thread layout: 256 thr; tx=tid&31 owns col-quads 4tx(+128); ty=tid>>5 owns
// RPT=BM/8 rows. X reads from LDS are lane-broadcast; W reads b128 at the
// bandwidth floor. BK=16 K-chunks keep static LDS at 51 KB -> 3 blocks/CU.
// ---------------------------------------------------------------------------
template <int BM>
__launch_bounds__(256, 2)
__global__ void mlp_fused(const float* __restrict__ p0, const float* __restrict__ p1,
                          const float* __restrict__ p2,
                          const int* __restrict__ i0, const int* __restrict__ i1,
                          const float* __restrict__ W1, const float* __restrict__ b1,
                          const float* __restrict__ g1, const float* __restrict__ be1,
                          const float* __restrict__ W2, const float* __restrict__ b2,
                          const float* __restrict__ g2, const float* __restrict__ be2,
                          const float* __restrict__ resid, float* __restrict__ outp,
                          int nrows, int act) {
  static_assert(BM % 8 == 0, "BM must be multiple of 8");
  constexpr int RPT = BM / 8;
  constexpr int XST = 24;               // Xs row stride (16 k + pad, 16B-aligned)
  __shared__ float Xs[BM * XST];        // BM x 16 staged X chunk
  __shared__ float Ws[16 * HID];        // 16x256 (phase1) / 16x128 (phase2 reuse)
  __shared__ float Hs[BM * HID];        // BM x 256 hidden activations

  const int tid = threadIdx.x;
  const int tx = tid & 31;
  const int ty = tid >> 5;
  const int row0 = blockIdx.x * BM;

  float acc[RPT][8];
  #pragma unroll
  for (int i = 0; i < RPT; ++i)
    #pragma unroll
    for (int j = 0; j < 8; ++j) acc[i][j] = 0.f;

  // ---- phase 1: X @ W1, K = 384 in 24 chunks of 16 ----
  for (int it = 0; it < 24; ++it) {
    const int koff = it * 16;
    const float* src;
    const int* idx;
    if (it < 8)       { src = p0; idx = i0; }
    else if (it < 16) { src = p1; idx = i1; }
    else              { src = p2; idx = nullptr; }
    const int c0 = koff & 127;
    __syncthreads();
    for (int q = tid; q < BM * 4; q += 256) {   // stage X: BM rows x 4 float4
      int r = q >> 2, j = q & 3;
      int grow = row0 + r;
      float4 v = make_float4(0.f, 0.f, 0.f, 0.f);
      if (grow < nrows) {
        int rr = idx ? idx[grow] : grow;
        v = *reinterpret_cast<const float4*>(src + (size_t)rr * LF + c0 + 4 * j);
      }
      *reinterpret_cast<float4*>(Xs + r * XST + 4 * j) = v;
    }
    for (int q = tid; q < 16 * 64; q += 256) {  // stage W1 chunk: 16 x 256
      int kk = q >> 6, c4 = q & 63;
      *reinterpret_cast<float4*>(Ws + kk * HID + 4 * c4) =
          *reinterpret_cast<const float4*>(W1 + (size_t)(koff + kk) * HID + 4 * c4);
    }
    __syncthreads();
    #pragma unroll
    for (int k4 = 0; k4 < 4; ++k4) {
      float4 xv[RPT];
      #pragma unroll
      for (int i = 0; i < RPT; ++i)
        xv[i] = *reinterpret_cast<const float4*>(Xs + (ty * RPT + i) * XST + 4 * k4);
      #pragma unroll
      for (int q = 0; q < 4; ++q) {
        const int kk = 4 * k4 + q;
        float4 w0 = *reinterpret_cast<const float4*>(Ws + kk * HID + 4 * tx);
        float4 w1 = *reinterpret_cast<const float4*>(Ws + kk * HID + 128 + 4 * tx);
        #pragma unroll
        for (int i = 0; i < RPT; ++i) {
          float x = (q == 0) ? xv[i].x : (q == 1) ? xv[i].y : (q == 2) ? xv[i].z : xv[i].w;
          acc[i][0] += x * w0.x; acc[i][1] += x * w0.y;
          acc[i][2] += x * w0.z; acc[i][3] += x * w0.w;
          acc[i][4] += x * w1.x; acc[i][5] += x * w1.y;
          acc[i][6] += x * w1.z; acc[i][7] += x * w1.w;
        }
      }
    }
  }

  // ---- epilogue 1: bias + LN + ReLU -> Hs ----
  float bb[8], gg[8], ee[8];
  #pragma unroll
  for (int j = 0; j < 8; ++j) {
    int c = 4 * tx + ((j < 4) ? j : (124 + j));   // cols 4tx+j and 128+4tx+(j-4)
    bb[j] = b1[c]; gg[j] = g1[c]; ee[j] = be1[c];
  }
  #pragma unroll
  for (int i = 0; i < RPT; ++i) {
    float s = 0.f, ss = 0.f;
    #pragma unroll
    for (int j = 0; j < 8; ++j) { acc[i][j] += bb[j]; s += acc[i][j]; }
    #pragma unroll
    for (int j = 0; j < 8; ++j) ss += acc[i][j] * acc[i][j];
    #pragma unroll
    for (int m = 1; m < 32; m <<= 1) {
      s += __shfl_xor(s, m, 64);
      ss += __shfl_xor(ss, m, 64);
    }
    const float mean = s * (1.f / HID);
    const float var = ss * (1.f / HID) - mean * mean;
    const float rstd = rsqrtf(var + 1e-5f);
    float hv[8];
    #pragma unroll
    for (int j = 0; j < 8; ++j)
      hv[j] = fmaxf((acc[i][j] - mean) * rstd * gg[j] + ee[j], 0.f);
    *reinterpret_cast<float4*>(Hs + (ty * RPT + i) * HID + 4 * tx) =
        make_float4(hv[0], hv[1], hv[2], hv[3]);
    *reinterpret_cast<float4*>(Hs + (ty * RPT + i) * HID + 128 + 4 * tx) =
        make_float4(hv[4], hv[5], hv[6], hv[7]);
  }

  // ---- phase 2: H @ W2, K = 256 in 16 chunks of 16 ----
  float acc2[RPT][4];
  #pragma unroll
  for (int i = 0; i < RPT; ++i)
    #pragma unroll
    for (int j = 0; j < 4; ++j) acc2[i][j] = 0.f;

  for (int it = 0; it < 16; ++it) {
    const int koff = it * 16;
    __syncthreads();                            // Ws reuse + (it==0) Hs visibility
    for (int q = tid; q < 16 * 32; q += 256) {  // stage W2 chunk: 16 x 128
      int kk = q >> 5, c4 = q & 31;
      *reinterpret_cast<float4*>(Ws + kk * LF + 4 * c4) =
          *reinterpret_cast<const float4*>(W2 + (size_t)(koff + kk) * LF + 4 * c4);
    }
    __syncthreads();
    #pragma unroll
    for (int k4 = 0; k4 < 4; ++k4) {
      float4 xv[RPT];
      #pragma unroll
      for (int i = 0; i < RPT; ++i)
        xv[i] = *reinterpret_cast<const float4*>(Hs + (ty * RPT + i) * HID + koff + 4 * k4);
      #pragma unroll
      for (int q = 0; q < 4; ++q) {
        const int kk = 4 * k4 + q;
        float4 w = *reinterpret_cast<const float4*>(Ws + kk * LF + 4 * tx);
        #pragma unroll
        for (int i = 0; i < RPT; ++i) {
          float x = (q == 0) ? xv[i].x : (q == 1) ? xv[i].y : (q == 2) ? xv[i].z : xv[i].w;
          acc2[i][0] += x * w.x; acc2[i][1] += x * w.y;
          acc2[i][2] += x * w.z; acc2[i][3] += x * w.w;
        }
      }
    }
  }

  // ---- epilogue 2: bias + LN + act + residual -> out ----
  float b2v[4], g2v[4], e2v[4];
  #pragma unroll
  for (int j = 0; j < 4; ++j) {
    int c = 4 * tx + j;
    b2v[j] = b2[c]; g2v[j] = g2[c]; e2v[j] = be2[c];
  }
  #pragma unroll
  for (int i = 0; i < RPT; ++i) {
    float s = 0.f, ss = 0.f;
    #pragma unroll
    for (int j = 0; j < 4; ++j) { acc2[i][j] += b2v[j]; s += acc2[i][j]; }
    #pragma unroll
    for (int j = 0; j < 4; ++j) ss += acc2[i][j] * acc2[i][j];
    #pragma unroll
    for (int m = 1; m < 32; m <<= 1) {
      s += __shfl_xor(s, m, 64);
      ss += __shfl_xor(ss, m, 64);
    }
    const float mean = s * (1.f / LF);
    const float var = ss * (1.f / LF) - mean * mean;
    const float rstd = rsqrtf(var + 1e-5f);
    const int grow = row0 + ty * RPT + i;
    if (grow < nrows) {
      float4 rv = *reinterpret_cast<const float4*>(resid + (size_t)grow * LF + 4 * tx);
      float o[4];
      #pragma unroll
      for (int j = 0; j < 4; ++j) {
        float v = (acc2[i][j] - mean) * rstd * g2v[j] + e2v[j];
        o[j] = act ? tanhf(v) : fmaxf(v, 0.f);
      }
      *reinterpret_cast<float4*>(outp + (size_t)grow * LF + 4 * tx) =
          make_float4(o[0] + rv.x, o[1] + rv.y, o[2] + rv.z, o[3] + rv.w);
    }
  }
}

// ---------------------------------------------------------------------------
extern "C" void kernel_launch(void* const* d_in, const int* in_sizes, int n_in,
                              void* d_out, int out_size, void* d_ws, size_t ws_size,
                              hipStream_t stream) {
  const float* nodes      = (const float*)d_in[0];
  const float* edges      = (const float*)d_in[1];
  const float* supernodes = (const float*)d_in[2];
  const float* superedges = (const float*)d_in[3];
  const float* ew   = (const float*)d_in[4];
  const float* bew  = (const float*)d_in[5];
  const float* sew  = (const float*)d_in[6];
  const float* W1   = (const float*)d_in[7];
  const float* b1   = (const float*)d_in[8];
  const float* g1w  = (const float*)d_in[9];
  const float* be1  = (const float*)d_in[10];
  const float* W2   = (const float*)d_in[11];
  const float* b2   = (const float*)d_in[12];
  const float* g2w  = (const float*)d_in[13];
  const float* be2  = (const float*)d_in[14];
  const int* graph  = (const int*)d_in[15];
  const int* bgraph = (const int*)d_in[16];
  const int* sgraph = (const int*)d_in[17];
  const int *g0 = graph,  *g1i = graph + EE;
  const int *bg0 = bgraph, *bg1 = bgraph + EBB;
  const int *sg0 = sgraph, *sg1 = sgraph + ESS;

  float* out_nodes = (float*)d_out;
  float* out_edges = out_nodes + (size_t)NN * LF;
  float* out_sn    = out_edges + (size_t)EE * LF;
  float* out_se    = out_sn + (size_t)SS * LF;

  // Message buffers live in d_out regions that are only written later:
  float* node_msg = out_se;                       // consumed by MLP0, before MLP2 writes se
  float* attn_msg = out_se + (size_t)SS * LF;
  float* sn_msg   = out_edges;                    // consumed by MLP1, before MLP3 writes edges
  float* edge_msg = out_edges + (size_t)NN * LF;

  // Sort scratch lives in the nodes region (written only by MLP1, after use):
  int* sc = (int*)d_out;
  size_t o = 0;
  int* h_bn  = sc + o; o += SS;
  int* h_se  = sc + o; o += SS;
  int* h_g1  = sc + o; o += NN;
  int* h_bg0 = sc + o; o += NN;
  const size_t histSpan = o;
  int* o_bn  = sc + o; o += SS + 1;
  int* o_se  = sc + o; o += SS + 1;
  int* o_g1  = sc + o; o += NN + 1;
  int* o_bg0 = sc + o; o += NN + 1;
  int* c_bn  = sc + o; o += SS;
  int* c_se  = sc + o; o += SS;
  int* c_g1  = sc + o; o += NN;
  int* c_bg0 = sc + o; o += NN;
  int* cs_bn = sc + o; o += 128;
  int* cs_se = sc + o; o += 128;
  int* cs_g1 = sc + o; o += 128;
  int* cs_bg0= sc + o; o += 128;
  int* ord_bn  = sc + o; o += EBB;
  int* ord_se  = sc + o; o += ESS;
  int* ord_g1  = sc + o; o += EE;
  int* ord_bg0 = sc + o; o += EBB;
  (void)d_ws; (void)ws_size; (void)in_sizes; (void)n_in; (void)out_size;

  hipMemsetAsync(sc, 0, histSpan * sizeof(int), stream);

  // --- counting sorts (index-only atomics) ---
  k_hist<<<512, 256, 0, stream>>>(bg1, EBB, h_bn);
  k_hist<<<512, 256, 0, stream>>>(sg1, ESS, h_se);
  k_hist<<<512, 256, 0, stream>>>(g1i, EE, h_g1);
  k_hist<<<512, 256, 0, stream>>>(bg0, EBB, h_bg0);

  auto scan3 = [&](int* hist, int n, int* off, int* csum, int* cur) {
    int nch = (n + 1023) / 1024;
    k_scanA<<<nch, 1024, 0, stream>>>(hist, n, off, csum);
    k_scanB<<<1, 64, 0, stream>>>(csum, nch);
    k_scanC<<<(n + 255) / 256, 256, 0, stream>>>(off, hist, csum, n, cur);
  };
  scan3(h_bn, SS, o_bn, cs_bn, c_bn);
  scan3(h_se, SS, o_se, cs_se, c_se);
  scan3(h_g1, NN, o_g1, cs_g1, c_g1);
  scan3(h_bg0, NN, o_bg0, cs_bg0, c_bg0);

  k_scatter<<<512, 256, 0, stream>>>(bg1, EBB, c_bn, ord_bn);
  k_scatter<<<512, 256, 0, stream>>>(sg1, ESS, c_se, ord_se);
  k_scatter<<<512, 256, 0, stream>>>(g1i, EE, c_g1, ord_g1);
  k_scatter<<<512, 256, 0, stream>>>(bg0, EBB, c_bg0, ord_bg0);

  // --- supernode update ---
  k_gather<<<SS, 128, 0, stream>>>(o_bn, ord_bn, bg0, bew, nodes, node_msg);
  k_gather<<<SS, 128, 0, stream>>>(o_se, ord_se, sg0, sew, superedges, attn_msg);
  mlp_fused<8><<<SS / 8, 256, 0, stream>>>(
      supernodes, attn_msg, node_msg, nullptr, nullptr,
      W1, b1, g1w, be1, W2, b2, g2w, be2,
      supernodes, out_sn, SS, 0);

  // --- node update ---
  k_gather<<<NN, 128, 0, stream>>>(o_bg0, ord_bg0, bg1, bew, out_sn, sn_msg);
  k_gather<<<NN, 128, 0, stream>>>(o_g1, ord_g1, nullptr, ew, edges, edge_msg);
  mlp_fused<32><<<(NN + 31) / 32, 256, 0, stream>>>(
      nodes, edge_msg, sn_msg, nullptr, nullptr,
      W1 + 1 * 384 * 256, b1 + 256, g1w + 256, be1 + 256,
      W2 + 1 * 256 * 128, b2 + 128, g2w + 128, be2 + 128,
      nodes, out_nodes, NN, 0);

  // --- superedge update ---
  mlp_fused<32><<<(ESS + 31) / 32, 256, 0, stream>>>(
      out_sn, out_sn, superedges, sg0, sg1,
      W1 + 2 * 384 * 256, b1 + 512, g1w + 512, be1 + 512,
      W2 + 2 * 256 * 128, b2 + 256, g2w + 256, be2 + 256,
      superedges, out_se, ESS, 1);

  // --- edge update ---
  mlp_fused<32><<<EE / 32, 256, 0, stream>>>(
      out_nodes, out_nodes, edges, g0, g1i,
      W1 + 3 * 384 * 256, b1 + 768, g1w + 768, be1 + 768,
      W2 + 3 * 256 * 128, b2 + 384, g2w + 384, be2 + 384,
      edges, out_edges, EE, 1);
}

// Round 3
// 1611.863 us; speedup vs baseline: 2.7152x; 2.7152x over previous
//
#include <hip/hip_runtime.h>
#include <cstddef>
#include <cstdint>

// Problem constants (fixed shapes from the reference)
constexpr int NN  = 100000;   // nodes
constexpr int EE  = 400000;   // edges
constexpr int SS  = 1024;     // supernodes
constexpr int EBB = 400000;   // bipartite edges
constexpr int ESS = 50000;    // superedges
constexpr int LF  = 128;      // feature dim
constexpr int HID = 256;      // hidden dim

typedef __attribute__((ext_vector_type(8))) short short8v;
typedef __attribute__((ext_vector_type(4))) float f32x4;

__device__ __forceinline__ uint16_t bf16rne(float f) {
  uint32_t u = __builtin_bit_cast(uint32_t, f);
  return (uint16_t)((u + 0x7FFFu + ((u >> 16) & 1u)) >> 16);
}

__device__ __forceinline__ void gload_lds16(const void* g, void* l) {
  __builtin_amdgcn_global_load_lds(
      (const __attribute__((address_space(1))) void*)g,
      (__attribute__((address_space(3))) void*)l, 16, 0, 0);
}

// ---------------------------------------------------------------------------
// Counting-sort infrastructure (index-only atomics; values summed atomic-free)
// ---------------------------------------------------------------------------
__global__ void k_hist(const int* __restrict__ idx, int n, int* __restrict__ hist) {
  for (int e = blockIdx.x * blockDim.x + threadIdx.x; e < n; e += gridDim.x * blockDim.x)
    atomicAdd(&hist[idx[e]], 1);
}

__global__ void k_scanA(const int* __restrict__ hist, int n,
                        int* __restrict__ off, int* __restrict__ csum) {
  __shared__ int sd[1024];
  const int t = threadIdx.x;
  const int i = blockIdx.x * 1024 + t;
  int v = (i < n) ? hist[i] : 0;
  sd[t] = v;
  __syncthreads();
  for (int d = 1; d < 1024; d <<= 1) {
    int addv = (t >= d) ? sd[t - d] : 0;
    __syncthreads();
    sd[t] += addv;
    __syncthreads();
  }
  if (i < n) off[i] = sd[t] - v;
  if (t == 1023) csum[blockIdx.x] = sd[t];
}

__global__ void k_scanB(int* __restrict__ csum, int nchunks) {
  if (threadIdx.x == 0 && blockIdx.x == 0) {
    int run = 0;
    for (int i = 0; i < nchunks; ++i) { int v = csum[i]; csum[i] = run; run += v; }
  }
}

__global__ void k_scanC(int* __restrict__ off, const int* __restrict__ hist,
                        const int* __restrict__ csum, int n, int* __restrict__ cur) {
  const int i = blockIdx.x * blockDim.x + threadIdx.x;
  if (i < n) {
    int o = off[i] + csum[i >> 10];
    off[i] = o;
    cur[i] = o;
    if (i == n - 1) off[n] = o + hist[i];
  }
}

__global__ void k_scatter(const int* __restrict__ idx, int n,
                          int* __restrict__ cur, int* __restrict__ order) {
  for (int e = blockIdx.x * blockDim.x + threadIdx.x; e < n; e += gridDim.x * blockDim.x) {
    int d = idx[e];
    int p = atomicAdd(&cur[d], 1);
    order[p] = e;
  }
}

// out[s][c] = sum_{e in seg(s)} w[e] * src[rowidx?rowidx[e]:e][c]
__global__ void k_gather(const int* __restrict__ off, const int* __restrict__ order,
                         const int* __restrict__ rowidx, const float* __restrict__ w,
                         const float* __restrict__ src, float* __restrict__ out) {
  const int s = blockIdx.x;
  const int c = threadIdx.x;
  const int p0 = off[s], p1 = off[s + 1];
  float acc = 0.f;
  #pragma unroll 4
  for (int p = p0; p < p1; ++p) {
    int e = order[p];
    int r = rowidx ? rowidx[e] : e;
    acc += w[e] * src[(size_t)r * LF + c];
  }
  out[(size_t)s * LF + c] = acc;
}

// ---------------------------------------------------------------------------
// Weight prepass: fp32 row-major -> bf16 n-major (so B-frags read k-contiguous)
// W1T: [4][256][384], W2T: [4][128][256]
// ---------------------------------------------------------------------------
__global__ void k_wt(const float* __restrict__ W1, const float* __restrict__ W2,
                     uint16_t* __restrict__ W1T, uint16_t* __restrict__ W2T) {
  int id = blockIdx.x * 256 + threadIdx.x;
  if (id < 4 * 256 * 384) {
    int m = id / (256 * 384); int r = id - m * (256 * 384);
    int n = r / 384;          int k = r - n * 384;
    W1T[id] = bf16rne(W1[((size_t)m * 384 + k) * 256 + n]);
  }
  if (id < 4 * 128 * 256) {
    int m = id / (128 * 256); int r = id - m * (128 * 256);
    int n = r / 256;          int k = r - n * 256;
    W2T[id] = bf16rne(W2[((size_t)m * 256 + k) * 128 + n]);
  }
}

// ---------------------------------------------------------------------------
// MFMA MLP: 64 rows/block, 4 waves x 16 rows. bf16 inputs, fp32 acc/LN/resid.
// Phase1: K=384 in 12 chunks of 32 -> 16x16x32 MFMA, N=256 (16 tiles/wave).
// Epilogue1: bias+LN+ReLU via 16-lane shfl tree -> bf16 Hs (swizzled LDS).
// Phase2: K=256 in 8 chunks, N=128 (8 tiles). Epilogue2: bias+LN+act+resid.
// All LDS tiles k-contiguous with 16B-group XOR swizzle (read==write perm).
// ---------------------------------------------------------------------------
__launch_bounds__(256, 3)
__global__ void mlp_mfma(const float* __restrict__ p0, const float* __restrict__ p1,
                         const float* __restrict__ p2,
                         const int* __restrict__ i0, const int* __restrict__ i1,
                         const uint16_t* __restrict__ W1T, const float* __restrict__ b1,
                         const float* __restrict__ g1, const float* __restrict__ be1,
                         const uint16_t* __restrict__ W2T, const float* __restrict__ b2,
                         const float* __restrict__ g2, const float* __restrict__ be2,
                         const float* __restrict__ resid, float* __restrict__ outp,
                         int nrows, int act) {
  __shared__ uint16_t Xs[64 * 32];     // 4 KB  [row][k] bf16, swizzled
  __shared__ uint16_t Ws[256 * 32];    // 16 KB [n][k] bf16, swizzled (both phases)
  __shared__ uint16_t Hs[64 * 256];    // 32 KB [row][k] bf16, swizzled

  const int tid = threadIdx.x;
  const int wv  = tid >> 6;       // wave 0..3
  const int ln  = tid & 63;
  const int m16 = ln & 15;        // A-row / B-col / D-col lane index
  const int kgp = ln >> 4;        // 8-elem k-group 0..3
  const int row0 = blockIdx.x * 64;
  const int sr = tid >> 2, spart = tid & 3;   // X staging: row, 8-float part
  const int wr = ln >> 2,  wc = ln & 3;       // W staging: row-in-16, 16B slot

  f32x4 acc[16];
  #pragma unroll
  for (int t = 0; t < 16; ++t) acc[t] = (f32x4){0.f, 0.f, 0.f, 0.f};

  // ---- phase 1: X @ W1 ----
  for (int it = 0; it < 12; ++it) {
    const float* src; const int* idx;
    if (it < 4)      { src = p0; idx = i0; }
    else if (it < 8) { src = p1; idx = i1; }
    else             { src = p2; idx = nullptr; }
    const int c0 = (it & 3) * 32;

    __syncthreads();
    {  // stage X chunk [64][32] fp32->bf16
      const int grow = row0 + sr;
      int rr = 0;
      if (grow < nrows) rr = idx ? idx[grow] : grow;
      const float* s = src + (size_t)rr * LF + c0 + spart * 8;
      const float4 v0 = *reinterpret_cast<const float4*>(s);
      const float4 v1 = *reinterpret_cast<const float4*>(s + 4);
      uint4 w;
      w.x = bf16rne(v0.x) | ((uint32_t)bf16rne(v0.y) << 16);
      w.y = bf16rne(v0.z) | ((uint32_t)bf16rne(v0.w) << 16);
      w.z = bf16rne(v1.x) | ((uint32_t)bf16rne(v1.y) << 16);
      w.w = bf16rne(v1.z) | ((uint32_t)bf16rne(v1.w) << 16);
      *reinterpret_cast<uint4*>(&Xs[sr * 32 + ((spart ^ (sr & 3)) * 8)]) = w;
    }
    // stage W1T chunk [256][32] bf16 direct-to-LDS (source pre-swizzled)
    #pragma unroll
    for (int q = 0; q < 4; ++q) {
      const int n0 = (wv * 4 + q) * 16;
      const int n  = n0 + wr;
      gload_lds16(W1T + (size_t)n * 384 + it * 32 + ((wc ^ (n & 3)) * 8), &Ws[n0 * 32]);
    }
    __syncthreads();

    const short8v a = *reinterpret_cast<const short8v*>(
        &Xs[(wv * 16 + m16) * 32 + ((kgp ^ (m16 & 3)) * 8)]);
    #pragma unroll
    for (int t = 0; t < 16; ++t) {
      const int n = t * 16 + m16;
      const short8v b = *reinterpret_cast<const short8v*>(
          &Ws[n * 32 + ((kgp ^ (n & 3)) * 8)]);
      acc[t] = __builtin_amdgcn_mfma_f32_16x16x32_bf16(a, b, acc[t], 0, 0, 0);
    }
  }

  // ---- epilogue 1: bias + LN + ReLU -> Hs (bf16) ----
  {
    float b1v[16];
    #pragma unroll
    for (int t = 0; t < 16; ++t) b1v[t] = b1[t * 16 + m16];
    float s[4] = {0, 0, 0, 0}, qq[4] = {0, 0, 0, 0};
    #pragma unroll
    for (int t = 0; t < 16; ++t)
      #pragma unroll
      for (int i = 0; i < 4; ++i) {
        acc[t][i] += b1v[t];
        s[i]  += acc[t][i];
        qq[i] += acc[t][i] * acc[t][i];
      }
    float mean[4], rstd[4];
    #pragma unroll
    for (int i = 0; i < 4; ++i) {
      #pragma unroll
      for (int msk = 1; msk < 16; msk <<= 1) {
        s[i]  += __shfl_xor(s[i], msk, 64);
        qq[i] += __shfl_xor(qq[i], msk, 64);
      }
      mean[i] = s[i] * (1.f / HID);
      float var = qq[i] * (1.f / HID) - mean[i] * mean[i];
      rstd[i] = rsqrtf(var + 1e-5f);
    }
    #pragma unroll
    for (int t = 0; t < 16; ++t) {
      const int col = t * 16 + m16;
      const float gv = g1[col], ev = be1[col];
      #pragma unroll
      for (int i = 0; i < 4; ++i) {
        const int row = wv * 16 + 4 * kgp + i;   // D-layout: row = 4*(lane>>4)+reg
        float h = (acc[t][i] - mean[i]) * rstd[i] * gv + ev;
        h = fmaxf(h, 0.f);
        Hs[row * 256 + (((col >> 3) ^ (row & 15)) * 8) + (col & 7)] = bf16rne(h);
      }
    }
  }

  // ---- phase 2: H @ W2 ----
  f32x4 acc2[8];
  #pragma unroll
  for (int t = 0; t < 8; ++t) acc2[t] = (f32x4){0.f, 0.f, 0.f, 0.f};

  for (int kc = 0; kc < 8; ++kc) {
    __syncthreads();
    #pragma unroll
    for (int q = 0; q < 2; ++q) {
      const int n0 = (wv * 2 + q) * 16;
      const int n  = n0 + wr;
      gload_lds16(W2T + (size_t)n * 256 + kc * 32 + ((wc ^ (n & 3)) * 8), &Ws[n0 * 32]);
    }
    __syncthreads();
    const int hrow = wv * 16 + m16;
    const short8v a = *reinterpret_cast<const short8v*>(
        &Hs[hrow * 256 + (((kc * 4 + kgp) ^ (hrow & 15)) * 8)]);
    #pragma unroll
    for (int t = 0; t < 8; ++t) {
      const int n = t * 16 + m16;
      const short8v b = *reinterpret_cast<const short8v*>(
          &Ws[n * 32 + ((kgp ^ (n & 3)) * 8)]);
      acc2[t] = __builtin_amdgcn_mfma_f32_16x16x32_bf16(a, b, acc2[t], 0, 0, 0);
    }
  }

  // ---- epilogue 2: bias + LN + act + residual -> out ----
  {
    float b2v[8];
    #pragma unroll
    for (int t = 0; t < 8; ++t) b2v[t] = b2[t * 16 + m16];
    float s[4] = {0, 0, 0, 0}, qq[4] = {0, 0, 0, 0};
    #pragma unroll
    for (int t = 0; t < 8; ++t)
      #pragma unroll
      for (int i = 0; i < 4; ++i) {
        acc2[t][i] += b2v[t];
        s[i]  += acc2[t][i];
        qq[i] += acc2[t][i] * acc2[t][i];
      }
    float mean2[4], rstd2[4];
    #pragma unroll
    for (int i = 0; i < 4; ++i) {
      #pragma unroll
      for (int msk = 1; msk < 16; msk <<= 1) {
        s[i]  += __shfl_xor(s[i], msk, 64);
        qq[i] += __shfl_xor(qq[i], msk, 64);
      }
      mean2[i] = s[i] * (1.f / LF);
      float var = qq[i] * (1.f / LF) - mean2[i] * mean2[i];
      rstd2[i] = rsqrtf(var + 1e-5f);
    }
    #pragma unroll
    for (int t = 0; t < 8; ++t) {
      const int col = t * 16 + m16;
      const float gv = g2[col], ev = be2[col];
      #pragma unroll
      for (int i = 0; i < 4; ++i) {
        const int row = wv * 16 + 4 * kgp + i;
        const int grow = row0 + row;
        if (grow < nrows) {
          float o = (acc2[t][i] - mean2[i]) * rstd2[i] * gv + ev;
          o = act ? tanhf(o) : fmaxf(o, 0.f);
          outp[(size_t)grow * LF + col] = o + resid[(size_t)grow * LF + col];
        }
      }
    }
  }
}

// ---------------------------------------------------------------------------
extern "C" void kernel_launch(void* const* d_in, const int* in_sizes, int n_in,
                              void* d_out, int out_size, void* d_ws, size_t ws_size,
                              hipStream_t stream) {
  const float* nodes      = (const float*)d_in[0];
  const float* edges      = (const float*)d_in[1];
  const float* supernodes = (const float*)d_in[2];
  const float* superedges = (const float*)d_in[3];
  const float* ew   = (const float*)d_in[4];
  const float* bew  = (const float*)d_in[5];
  const float* sew  = (const float*)d_in[6];
  const float* W1   = (const float*)d_in[7];
  const float* b1   = (const float*)d_in[8];
  const float* g1w  = (const float*)d_in[9];
  const float* be1  = (const float*)d_in[10];
  const float* W2   = (const float*)d_in[11];
  const float* b2   = (const float*)d_in[12];
  const float* g2w  = (const float*)d_in[13];
  const float* be2  = (const float*)d_in[14];
  const int* graph  = (const int*)d_in[15];
  const int* bgraph = (const int*)d_in[16];
  const int* sgraph = (const int*)d_in[17];
  const int *g0 = graph,  *g1i = graph + EE;
  const int *bg0 = bgraph, *bg1 = bgraph + EBB;
  const int *sg0 = sgraph, *sg1 = sgraph + ESS;

  float* out_nodes = (float*)d_out;
  float* out_edges = out_nodes + (size_t)NN * LF;
  float* out_sn    = out_edges + (size_t)EE * LF;
  float* out_se    = out_sn + (size_t)SS * LF;

  // Message buffers live in d_out regions that are only written later:
  float* node_msg = out_se;                       // consumed by MLP0, before MLP2 writes se
  float* attn_msg = out_se + (size_t)SS * LF;
  float* sn_msg   = out_edges;                    // consumed by MLP1, before MLP3 writes edges
  float* edge_msg = out_edges + (size_t)NN * LF;

  // bf16 transposed weights in d_ws (1 MB)
  uint16_t* W1T = (uint16_t*)d_ws;                // [4][256][384]
  uint16_t* W2T = W1T + 4 * 256 * 384;            // [4][128][256]

  // Sort scratch lives in the nodes region (written only by MLP1, after use):
  int* sc = (int*)d_out;
  size_t o = 0;
  int* h_bn  = sc + o; o += SS;
  int* h_se  = sc + o; o += SS;
  int* h_g1  = sc + o; o += NN;
  int* h_bg0 = sc + o; o += NN;
  const size_t histSpan = o;
  int* o_bn  = sc + o; o += SS + 1;
  int* o_se  = sc + o; o += SS + 1;
  int* o_g1  = sc + o; o += NN + 1;
  int* o_bg0 = sc + o; o += NN + 1;
  int* c_bn  = sc + o; o += SS;
  int* c_se  = sc + o; o += SS;
  int* c_g1  = sc + o; o += NN;
  int* c_bg0 = sc + o; o += NN;
  int* cs_bn = sc + o; o += 128;
  int* cs_se = sc + o; o += 128;
  int* cs_g1 = sc + o; o += 128;
  int* cs_bg0= sc + o; o += 128;
  int* ord_bn  = sc + o; o += EBB;
  int* ord_se  = sc + o; o += ESS;
  int* ord_g1  = sc + o; o += EE;
  int* ord_bg0 = sc + o; o += EBB;
  (void)d_ws; (void)ws_size; (void)in_sizes; (void)n_in; (void)out_size;

  hipMemsetAsync(sc, 0, histSpan * sizeof(int), stream);

  // weight prepass (independent; runs while sorts proceed)
  k_wt<<<(4 * 256 * 384 + 255) / 256, 256, 0, stream>>>(W1, W2, W1T, W2T);

  // --- counting sorts (index-only atomics) ---
  k_hist<<<512, 256, 0, stream>>>(bg1, EBB, h_bn);
  k_hist<<<512, 256, 0, stream>>>(sg1, ESS, h_se);
  k_hist<<<512, 256, 0, stream>>>(g1i, EE, h_g1);
  k_hist<<<512, 256, 0, stream>>>(bg0, EBB, h_bg0);

  auto scan3 = [&](int* hist, int n, int* off, int* csum, int* cur) {
    int nch = (n + 1023) / 1024;
    k_scanA<<<nch, 1024, 0, stream>>>(hist, n, off, csum);
    k_scanB<<<1, 64, 0, stream>>>(csum, nch);
    k_scanC<<<(n + 255) / 256, 256, 0, stream>>>(off, hist, csum, n, cur);
  };
  scan3(h_bn, SS, o_bn, cs_bn, c_bn);
  scan3(h_se, SS, o_se, cs_se, c_se);
  scan3(h_g1, NN, o_g1, cs_g1, c_g1);
  scan3(h_bg0, NN, o_bg0, cs_bg0, c_bg0);

  k_scatter<<<512, 256, 0, stream>>>(bg1, EBB, c_bn, ord_bn);
  k_scatter<<<512, 256, 0, stream>>>(sg1, ESS, c_se, ord_se);
  k_scatter<<<512, 256, 0, stream>>>(g1i, EE, c_g1, ord_g1);
  k_scatter<<<512, 256, 0, stream>>>(bg0, EBB, c_bg0, ord_bg0);

  // --- supernode update ---
  k_gather<<<SS, 128, 0, stream>>>(o_bn, ord_bn, bg0, bew, nodes, node_msg);
  k_gather<<<SS, 128, 0, stream>>>(o_se, ord_se, sg0, sew, superedges, attn_msg);
  mlp_mfma<<<SS / 64, 256, 0, stream>>>(
      supernodes, attn_msg, node_msg, nullptr, nullptr,
      W1T, b1, g1w, be1, W2T, b2, g2w, be2,
      supernodes, out_sn, SS, 0);

  // --- node update ---
  k_gather<<<NN, 128, 0, stream>>>(o_bg0, ord_bg0, bg1, bew, out_sn, sn_msg);
  k_gather<<<NN, 128, 0, stream>>>(o_g1, ord_g1, nullptr, ew, edges, edge_msg);
  mlp_mfma<<<(NN + 63) / 64, 256, 0, stream>>>(
      nodes, edge_msg, sn_msg, nullptr, nullptr,
      W1T + 1 * 256 * 384, b1 + 256, g1w + 256, be1 + 256,
      W2T + 1 * 128 * 256, b2 + 128, g2w + 128, be2 + 128,
      nodes, out_nodes, NN, 0);

  // --- superedge update ---
  mlp_mfma<<<(ESS + 63) / 64, 256, 0, stream>>>(
      out_sn, out_sn, superedges, sg0, sg1,
      W1T + 2 * 256 * 384, b1 + 512, g1w + 512, be1 + 512,
      W2T + 2 * 128 * 256, b2 + 256, g2w + 256, be2 + 256,
      superedges, out_se, ESS, 1);

  // --- edge update ---
  mlp_mfma<<<EE / 64, 256, 0, stream>>>(
      out_nodes, out_nodes, edges, g0, g1i,
      W1T + 3 * 256 * 384, b1 + 768, g1w + 768, be1 + 768,
      W2T + 3 * 128 * 256, b2 + 384, g2w + 384, be2 + 384,
      edges, out_edges, EE, 1);
}